// Round 1
// baseline (50.082 us; speedup 1.0000x reference)
//
#include <hip/hip_runtime.h>
#include <hip/hip_bf16.h>
#include <cstdint>
#include <cstddef>

typedef __bf16 bf16_t;
typedef __bf16 bf16x8 __attribute__((ext_vector_type(8)));
typedef __bf16 bf16x4 __attribute__((ext_vector_type(4)));
typedef float f32x4 __attribute__((ext_vector_type(4)));

#define NNODES 4096
#define EMB 512
#define NH 8
#define DT 64
#define DTOT 512  // NH*DT

// ---------------------------------------------------------------------------
// async global->LDS, 16B per lane. LDS dest must be wave-uniform base; HW
// scatters lane l to base + l*16 (guide §5). Global src is per-lane.
__device__ __forceinline__ void async_copy16(void* lds, const void* gsrc) {
  __builtin_amdgcn_global_load_lds(
      (const __attribute__((address_space(1))) void*)gsrc,
      (__attribute__((address_space(3))) void*)lds, 16, 0, 0);
}

// ---------------------------------------------------------------------------
// fp32 -> bf16 convert (x), vectorized float4 -> bf16x4
__global__ __launch_bounds__(256) void cvt_x_kernel(const float* __restrict__ in,
                                                    bf16_t* __restrict__ out, int n4) {
  int i = blockIdx.x * blockDim.x + threadIdx.x;
  if (i >= n4) return;
  float4 v = reinterpret_cast<const float4*>(in)[i];
  bf16x4 o = {(bf16_t)v.x, (bf16_t)v.y, (bf16_t)v.z, (bf16_t)v.w};
  reinterpret_cast<bf16x4*>(out)[i] = o;
}

// ---------------------------------------------------------------------------
// Transpose 512x512 fp32 weights -> bf16 [N][K] (so MFMA B-frags read
// contiguous K). 4 matrices (wq, wk, wv, wo), 64x64 tiles via LDS.
__global__ __launch_bounds__(256) void wtrans_kernel(
    const float* __restrict__ wq, const float* __restrict__ wk,
    const float* __restrict__ wv, const float* __restrict__ wo,
    bf16_t* __restrict__ wqkvT, bf16_t* __restrict__ woT) {
  __shared__ float tile[64][65];
  int mat = blockIdx.x >> 6;   // 0..3
  int t = blockIdx.x & 63;
  int kb = (t >> 3) << 6;      // k tile base
  int nb = (t & 7) << 6;       // n tile base
  const float* src = mat == 0 ? wq : mat == 1 ? wk : mat == 2 ? wv : wo;
  int c = threadIdx.x & 63;
  int r0 = threadIdx.x >> 6;   // 0..3
  for (int r = r0; r < 64; r += 4)
    tile[r][c] = src[(size_t)(kb + r) * EMB + nb + c];
  __syncthreads();
  bf16_t* dst = (mat < 3) ? (wqkvT + (size_t)mat * EMB * DTOT) : woT;
  for (int r = r0; r < 64; r += 4)
    dst[(size_t)(nb + r) * EMB + kb + c] = (bf16_t)tile[c][r];
}

// ---------------------------------------------------------------------------
// bf16 MFMA GEMM, 128x128 tile, BK=32, 256 threads (4 waves 2x2), m97-style
// global_load_lds staging (linear LDS, 2 barriers per K-step).
// MODE 0: A = x_bf16 [4096][512], B = wqkvT [1536][512]; epilogue adds per-
//         matrix bias and scatters bf16 to QKV head-major [3][8][4096][64].
// MODE 1: A = z [4096][512], B = woT [512][512]; epilogue adds b_o, fp32 out.
template <int MODE>
__global__ __launch_bounds__(256) void gemm_kernel(
    const bf16_t* __restrict__ A, const bf16_t* __restrict__ B,
    const float* __restrict__ bq, const float* __restrict__ bk,
    const float* __restrict__ bv, const float* __restrict__ bo,
    bf16_t* __restrict__ qkv, float* __restrict__ outp) {
  constexpr int K = 512;
  __shared__ __align__(16) bf16_t sA[128 * 32];
  __shared__ __align__(16) bf16_t sB[128 * 32];
  const int tid = threadIdx.x;
  const int l = tid & 63, w = tid >> 6;
  const int wm = w >> 1, wn = w & 1;
  const int arow0 = blockIdx.x * 128;
  const int bcol0 = blockIdx.y * 128;

  f32x4 acc[4][4];
#pragma unroll
  for (int m = 0; m < 4; ++m)
#pragma unroll
    for (int n = 0; n < 4; ++n) acc[m][n] = f32x4{0.f, 0.f, 0.f, 0.f};

  for (int kt = 0; kt < K; kt += 32) {
    // stage A,B tiles: 8192 B each; per issue a wave covers 1024 B
#pragma unroll
    for (int i = 0; i < 2; ++i) {
      int row = (i << 6) + (w << 4) + (l >> 2);  // 0..127
      int cole = (l & 3) << 3;                   // elem offset within 32
      int ldso = i * 2048 + w * 512;             // elems (bytes/2)
      async_copy16(&sA[ldso], &A[(size_t)(arow0 + row) * K + kt + cole]);
      async_copy16(&sB[ldso], &B[(size_t)(bcol0 + row) * K + kt + cole]);
    }
    __syncthreads();
    bf16x8 af[4], bfr[4];
#pragma unroll
    for (int m = 0; m < 4; ++m)
      af[m] = *(const bf16x8*)&sA[(wm * 64 + m * 16 + (l & 15)) * 32 + ((l >> 4) << 3)];
#pragma unroll
    for (int n = 0; n < 4; ++n)
      bfr[n] = *(const bf16x8*)&sB[(wn * 64 + n * 16 + (l & 15)) * 32 + ((l >> 4) << 3)];
#pragma unroll
    for (int m = 0; m < 4; ++m)
#pragma unroll
      for (int n = 0; n < 4; ++n)
        acc[m][n] = __builtin_amdgcn_mfma_f32_16x16x32_bf16(af[m], bfr[n], acc[m][n], 0, 0, 0);
    __syncthreads();
  }

  // epilogue: D row = (l>>4)*4 + r, col = l&15 (guide §3, m89-verified)
#pragma unroll
  for (int m = 0; m < 4; ++m) {
    int row0 = arow0 + wm * 64 + m * 16 + ((l >> 4) << 2);
#pragma unroll
    for (int n = 0; n < 4; ++n) {
      int col = bcol0 + wn * 64 + n * 16 + (l & 15);
      if (MODE == 0) {
        int mi = col >> 9;            // 0:q 1:k 2:v
        int hc = col & 511;
        const float* bp = mi == 0 ? bq : mi == 1 ? bk : bv;
        float bias = bp[hc];
        int head = hc >> 6, tt = hc & 63;
        bf16_t* base = qkv + (((size_t)mi * NH + head) * NNODES) * DT + tt;
#pragma unroll
        for (int r = 0; r < 4; ++r)
          base[(size_t)(row0 + r) * DT] = (bf16_t)(acc[m][n][r] + bias);
      } else {
        float bias = bo[col];
#pragma unroll
        for (int r = 0; r < 4; ++r)
          outp[(size_t)(row0 + r) * DTOT + col] = acc[m][n][r] + bias;
      }
    }
  }
}

// ---------------------------------------------------------------------------
// Attention. Block = 256 threads = 4 waves, each wave owns one row i.
// Fast path (beta[h]==0, block-uniform): z_row = alpha * v_row.
// General path: flash-style online softmax over 4096 cols with adj bias,
// diagonal fix z_i = b*(S_i) + (a - b*p_ii)*v_i.
__global__ __launch_bounds__(256) void attn_kernel(
    const bf16_t* __restrict__ qkv, const float* __restrict__ adj,
    const float* __restrict__ alpha, const float* __restrict__ beta,
    bf16_t* __restrict__ z) {
  const int h = blockIdx.y;
  const int wv_ = threadIdx.x >> 6;
  const int l = threadIdx.x & 63;
  const int i = blockIdx.x * 4 + wv_;
  const float a = alpha[h], b = beta[h];
  const size_t hoff = (size_t)h * NNODES * DT;
  const bf16_t* Q = qkv + hoff;
  const bf16_t* Kh = qkv + (size_t)NH * NNODES * DT + hoff;
  const bf16_t* V = qkv + (size_t)2 * NH * NNODES * DT + hoff;

  if (b == 0.0f) {  // block-uniform branch (h uniform per block)
    z[(size_t)i * DTOT + h * DT + l] = (bf16_t)(a * (float)V[(size_t)i * DT + l]);
    return;
  }

  // ---- general path (correct for any alpha/beta; slow, not hit here) ----
  __shared__ float qs[4][64];
  __shared__ float ps[4][64];
  qs[wv_][l] = (float)Q[(size_t)i * DT + l];
  float mr = -__builtin_inff(), sr = 0.f, zacc = 0.f, sii = -__builtin_inff();
  const float* adjrow = adj + ((size_t)h * NNODES + i) * NNODES;
  __syncthreads();
  for (int c0 = 0; c0 < NNODES; c0 += 64) {
    int j = c0 + l;
    float s = 0.f;
    const bf16_t* kp = Kh + (size_t)j * DT;
#pragma unroll
    for (int d = 0; d < 64; ++d) s += qs[wv_][d] * (float)kp[d];
    s = s * 0.125f + adjrow[j];
    if ((i >> 6) == (c0 >> 6)) sii = __shfl(s, i & 63, 64);  // raw diag score
    float cm = s;
#pragma unroll
    for (int o = 32; o; o >>= 1) cm = fmaxf(cm, __shfl_xor(cm, o, 64));
    float mn = fmaxf(mr, cm);
    float scale = expf(mr - mn);
    sr *= scale;
    zacc *= scale;
    float p = expf(s - mn);
    float cs = p;
#pragma unroll
    for (int o = 32; o; o >>= 1) cs += __shfl_xor(cs, o, 64);
    sr += cs;
    mr = mn;
    ps[wv_][l] = p;
    __syncthreads();
    float za = 0.f;
    for (int j2 = 0; j2 < 64; ++j2)
      za += ps[wv_][j2] * (float)V[(size_t)(c0 + j2) * DT + l];  // lane = dim
    zacc += za;
    __syncthreads();
  }
  float pii = expf(sii - mr) / sr;
  float vd = (float)V[(size_t)i * DT + l];
  float zd = b * (zacc / sr) + (a - b * pii) * vd;
  z[(size_t)i * DTOT + h * DT + l] = (bf16_t)zd;
}

// ---------------------------------------------------------------------------
extern "C" void kernel_launch(void* const* d_in, const int* in_sizes, int n_in,
                              void* d_out, int out_size, void* d_ws, size_t ws_size,
                              hipStream_t stream) {
  const float* x     = (const float*)d_in[0];
  const float* adj   = (const float*)d_in[1];
  const float* wq    = (const float*)d_in[2];
  const float* bq    = (const float*)d_in[3];
  const float* wk    = (const float*)d_in[4];
  const float* bk    = (const float*)d_in[5];
  const float* wv    = (const float*)d_in[6];
  const float* bv    = (const float*)d_in[7];
  const float* wo    = (const float*)d_in[8];
  const float* bo    = (const float*)d_in[9];
  const float* alpha = (const float*)d_in[10];
  const float* beta  = (const float*)d_in[11];
  float* out = (float*)d_out;
  char* ws = (char*)d_ws;

  bf16_t* xb    = (bf16_t*)(ws);                          // 4 MB
  bf16_t* wqkvT = (bf16_t*)(ws + (4u << 20));             // 1.5 MB
  bf16_t* woT   = (bf16_t*)(ws + (4u << 20) + 1572864u);  // 0.5 MB
  bf16_t* qkv   = (bf16_t*)(ws + (6u << 20));             // 12 MB
  bf16_t* z     = (bf16_t*)(ws + (18u << 20));            // 4 MB  (total 22 MB)

  hipLaunchKernelGGL(cvt_x_kernel, dim3(2048), dim3(256), 0, stream,
                     x, xb, NNODES * EMB / 4);
  hipLaunchKernelGGL(wtrans_kernel, dim3(256), dim3(256), 0, stream,
                     wq, wk, wv, wo, wqkvT, woT);
  hipLaunchKernelGGL((gemm_kernel<0>), dim3(32, 12), dim3(256), 0, stream,
                     xb, wqkvT, bq, bk, bv, nullptr, qkv, nullptr);
  hipLaunchKernelGGL(attn_kernel, dim3(NNODES / 4, NH), dim3(256), 0, stream,
                     qkv, adj, alpha, beta, z);
  hipLaunchKernelGGL((gemm_kernel<1>), dim3(32, 4), dim3(256), 0, stream,
                     z, woT, nullptr, nullptr, nullptr, bo, nullptr, out);
}

// Round 3
// 47.350 us; speedup vs baseline: 1.0577x; 1.0577x over previous
//
#include <hip/hip_runtime.h>
#include <hip/hip_bf16.h>
#include <cstdint>
#include <cstddef>

typedef __bf16 bf16_t;
typedef __bf16 bf16x8 __attribute__((ext_vector_type(8)));
typedef __bf16 bf16x4 __attribute__((ext_vector_type(4)));
typedef float f32x4 __attribute__((ext_vector_type(4)));

#define NNODES 4096
#define EMB 512
#define NH 8
#define DT 64
#define DTOT 512  // NH*DT

// ---------------------------------------------------------------------------
__device__ __forceinline__ void async_copy16(void* lds, const void* gsrc) {
  __builtin_amdgcn_global_load_lds(
      (const __attribute__((address_space(1))) void*)gsrc,
      (__attribute__((address_space(3))) void*)lds, 16, 0, 0);
}

__device__ __forceinline__ bool beta_all_zero(const float* __restrict__ beta) {
  bool z = true;
#pragma unroll
  for (int h = 0; h < NH; ++h) z = z && (beta[h] == 0.0f);
  return z;
}

// ---------------------------------------------------------------------------
// Fused prep: [0,2048) cvt x->bf16; [2048,2112) woT transpose; [2112,2176)
// wv_s = wv * alpha (row-major bf16); [2176,2178) b_eff; [2178,2370)
// general-only wq/wk/wv transposes into wqkvT.
__global__ __launch_bounds__(256) void prep_kernel(
    const float* __restrict__ x,
    const float* __restrict__ wq, const float* __restrict__ wk,
    const float* __restrict__ wv, const float* __restrict__ wo,
    const float* __restrict__ bv, const float* __restrict__ bo,
    const float* __restrict__ alpha, const float* __restrict__ beta,
    bf16_t* __restrict__ xb, bf16_t* __restrict__ wqkvT,
    bf16_t* __restrict__ woT, bf16_t* __restrict__ wv_s,
    float* __restrict__ b_eff) {
  __shared__ float tile[64][65];
  int b = blockIdx.x;
  const int tid = threadIdx.x;
  if (b < 2048) {  // x -> bf16
    int i = b * 256 + tid;
    float4 v = reinterpret_cast<const float4*>(x)[i];
    bf16x4 o = {(bf16_t)v.x, (bf16_t)v.y, (bf16_t)v.z, (bf16_t)v.w};
    reinterpret_cast<bf16x4*>(xb)[i] = o;
    return;
  }
  b -= 2048;
  if (b < 64) {  // woT[n_emb][d] = wo[d][n_emb]
    int kb = (b >> 3) << 6, nb = (b & 7) << 6;
    int c = tid & 63, r0 = tid >> 6;
    for (int r = r0; r < 64; r += 4)
      tile[r][c] = wo[(size_t)(kb + r) * EMB + nb + c];
    __syncthreads();
    for (int r = r0; r < 64; r += 4)
      woT[(size_t)(nb + r) * EMB + kb + c] = (bf16_t)tile[c][r];
    return;
  }
  b -= 64;
  if (b < 64) {  // wv_s[k][d] = wv[k][d] * alpha[d>>6], row-major bf16
#pragma unroll
    for (int t = 0; t < 4; ++t) {
      int i = b * 1024 + t * 256 + tid;
      float4 v = reinterpret_cast<const float4*>(wv)[i];
      float sc = alpha[(i & 127) >> 4];  // 128 float4 per row; 16 per head
      bf16x4 o = {(bf16_t)(v.x * sc), (bf16_t)(v.y * sc),
                  (bf16_t)(v.z * sc), (bf16_t)(v.w * sc)};
      reinterpret_cast<bf16x4*>(wv_s)[i] = o;
    }
    return;
  }
  b -= 64;
  if (b < 2) {  // b_eff[n] = bo[n] + sum_d bv[d]*alpha[h(d)]*wo[d][n]
    int n = b * 256 + tid;
    float s = bo[n];
    for (int d = 0; d < DTOT; ++d)
      s += bv[d] * alpha[d >> 6] * wo[(size_t)d * EMB + n];
    b_eff[n] = s;
    return;
  }
  b -= 2;
  if (beta_all_zero(beta)) return;  // general-mode only below
  int mat = b >> 6;  // 0=q 1=k 2=v
  int t2 = b & 63;
  const float* src = mat == 0 ? wq : mat == 1 ? wk : wv;
  int kb = (t2 >> 3) << 6, nb = (t2 & 7) << 6;
  int c = tid & 63, r0 = tid >> 6;
  for (int r = r0; r < 64; r += 4)
    tile[r][c] = src[(size_t)(kb + r) * EMB + nb + c];
  __syncthreads();
  bf16_t* dst = wqkvT + (size_t)mat * EMB * DTOT;
  for (int r = r0; r < 64; r += 4)
    dst[(size_t)(nb + r) * EMB + kb + c] = (bf16_t)tile[c][r];
}

// ---------------------------------------------------------------------------
// FAST ONLY: W_effT[n_out][k] = sum_d woT[n_out][d] * wv_s[k][d].
// 64x64 tiles, grid (8,8), 4 waves 2x2 each 32x32.
__global__ __launch_bounds__(256) void comp_gemm_kernel(
    const bf16_t* __restrict__ A, const bf16_t* __restrict__ B,
    const float* __restrict__ beta, bf16_t* __restrict__ w_effT) {
  if (!beta_all_zero(beta)) return;
  __shared__ __align__(16) bf16_t sA[64 * 32];
  __shared__ __align__(16) bf16_t sB[64 * 32];
  const int tid = threadIdx.x, l = tid & 63, w = tid >> 6;
  const int wm = w >> 1, wn = w & 1;
  const int row0b = blockIdx.x * 64, col0b = blockIdx.y * 64;
  f32x4 acc[2][2];
#pragma unroll
  for (int m = 0; m < 2; ++m)
#pragma unroll
    for (int n = 0; n < 2; ++n) acc[m][n] = f32x4{0.f, 0.f, 0.f, 0.f};
  for (int kt = 0; kt < EMB; kt += 32) {
    int row = w * 16 + (l >> 2);
    int cole = (l & 3) << 3;
    async_copy16(&sA[w * 512], &A[(size_t)(row0b + row) * EMB + kt + cole]);
    async_copy16(&sB[w * 512], &B[(size_t)(col0b + row) * EMB + kt + cole]);
    __syncthreads();
    bf16x8 af[2], bfr[2];
#pragma unroll
    for (int m = 0; m < 2; ++m)
      af[m] = *(const bf16x8*)&sA[(wm * 32 + m * 16 + (l & 15)) * 32 + ((l >> 4) << 3)];
#pragma unroll
    for (int n = 0; n < 2; ++n)
      bfr[n] = *(const bf16x8*)&sB[(wn * 32 + n * 16 + (l & 15)) * 32 + ((l >> 4) << 3)];
#pragma unroll
    for (int m = 0; m < 2; ++m)
#pragma unroll
      for (int n = 0; n < 2; ++n)
        acc[m][n] = __builtin_amdgcn_mfma_f32_16x16x32_bf16(af[m], bfr[n], acc[m][n], 0, 0, 0);
    __syncthreads();
  }
#pragma unroll
  for (int m = 0; m < 2; ++m) {
    int row0 = row0b + wm * 32 + m * 16 + ((l >> 4) << 2);
#pragma unroll
    for (int n = 0; n < 2; ++n) {
      int col = col0b + wn * 32 + n * 16 + (l & 15);
#pragma unroll
      for (int r = 0; r < 4; ++r)
        w_effT[(size_t)(row0 + r) * EMB + col] = (bf16_t)acc[m][n][r];
    }
  }
}

// ---------------------------------------------------------------------------
// FAST ONLY: out = xb @ W_effT^T + b_eff. M=4096,N=512,K=512.
// 64x128 tiles, grid (64,4), 4 waves 2x2: wave = 32 rows x 64 cols.
__global__ __launch_bounds__(256) void final_gemm_kernel(
    const bf16_t* __restrict__ A, const bf16_t* __restrict__ B,
    const float* __restrict__ b_eff, const float* __restrict__ beta,
    float* __restrict__ outp) {
  if (!beta_all_zero(beta)) return;
  __shared__ __align__(16) bf16_t sA[64 * 32];
  __shared__ __align__(16) bf16_t sB[128 * 32];
  const int tid = threadIdx.x, l = tid & 63, w = tid >> 6;
  const int wm = w >> 1, wn = w & 1;
  const int arow0 = blockIdx.x * 64, bcol0 = blockIdx.y * 128;
  f32x4 acc[2][4];
#pragma unroll
  for (int m = 0; m < 2; ++m)
#pragma unroll
    for (int n = 0; n < 4; ++n) acc[m][n] = f32x4{0.f, 0.f, 0.f, 0.f};
  for (int kt = 0; kt < EMB; kt += 32) {
    int cole = (l & 3) << 3;
    async_copy16(&sA[w * 512], &A[(size_t)(arow0 + w * 16 + (l >> 2)) * EMB + kt + cole]);
#pragma unroll
    for (int i = 0; i < 2; ++i)
      async_copy16(&sB[i * 2048 + w * 512],
                   &B[(size_t)(bcol0 + i * 64 + w * 16 + (l >> 2)) * EMB + kt + cole]);
    __syncthreads();
    bf16x8 af[2], bfr[4];
#pragma unroll
    for (int m = 0; m < 2; ++m)
      af[m] = *(const bf16x8*)&sA[(wm * 32 + m * 16 + (l & 15)) * 32 + ((l >> 4) << 3)];
#pragma unroll
    for (int n = 0; n < 4; ++n)
      bfr[n] = *(const bf16x8*)&sB[(wn * 64 + n * 16 + (l & 15)) * 32 + ((l >> 4) << 3)];
#pragma unroll
    for (int m = 0; m < 2; ++m)
#pragma unroll
      for (int n = 0; n < 4; ++n)
        acc[m][n] = __builtin_amdgcn_mfma_f32_16x16x32_bf16(af[m], bfr[n], acc[m][n], 0, 0, 0);
    __syncthreads();
  }
#pragma unroll
  for (int m = 0; m < 2; ++m) {
    int row0 = arow0 + wm * 32 + m * 16 + ((l >> 4) << 2);
#pragma unroll
    for (int n = 0; n < 4; ++n) {
      int col = bcol0 + wn * 64 + n * 16 + (l & 15);
      float bias = b_eff[col];
#pragma unroll
      for (int r = 0; r < 4; ++r)
        outp[(size_t)(row0 + r) * DTOT + col] = acc[m][n][r] + bias;
    }
  }
}

// ---------------------------------------------------------------------------
// GENERAL ONLY (dead-launch when all beta==0): QKV / output projection GEMM.
template <int MODE>
__global__ __launch_bounds__(256) void gemm_kernel(
    const bf16_t* __restrict__ A, const bf16_t* __restrict__ B,
    const float* __restrict__ bq, const float* __restrict__ bk,
    const float* __restrict__ bv, const float* __restrict__ bo,
    const float* __restrict__ beta,
    bf16_t* __restrict__ qkv, float* __restrict__ outp) {
  if (beta_all_zero(beta)) return;
  constexpr int K = 512;
  __shared__ __align__(16) bf16_t sA[128 * 32];
  __shared__ __align__(16) bf16_t sB[128 * 32];
  const int tid = threadIdx.x;
  const int l = tid & 63, w = tid >> 6;
  const int wm = w >> 1, wn = w & 1;
  const int arow0 = blockIdx.x * 128;
  const int bcol0 = blockIdx.y * 128;
  f32x4 acc[4][4];
#pragma unroll
  for (int m = 0; m < 4; ++m)
#pragma unroll
    for (int n = 0; n < 4; ++n) acc[m][n] = f32x4{0.f, 0.f, 0.f, 0.f};
  for (int kt = 0; kt < K; kt += 32) {
#pragma unroll
    for (int i = 0; i < 2; ++i) {
      int row = (i << 6) + (w << 4) + (l >> 2);
      int cole = (l & 3) << 3;
      int ldso = i * 2048 + w * 512;
      async_copy16(&sA[ldso], &A[(size_t)(arow0 + row) * K + kt + cole]);
      async_copy16(&sB[ldso], &B[(size_t)(bcol0 + row) * K + kt + cole]);
    }
    __syncthreads();
    bf16x8 af[4], bfr[4];
#pragma unroll
    for (int m = 0; m < 4; ++m)
      af[m] = *(const bf16x8*)&sA[(wm * 64 + m * 16 + (l & 15)) * 32 + ((l >> 4) << 3)];
#pragma unroll
    for (int n = 0; n < 4; ++n)
      bfr[n] = *(const bf16x8*)&sB[(wn * 64 + n * 16 + (l & 15)) * 32 + ((l >> 4) << 3)];
#pragma unroll
    for (int m = 0; m < 4; ++m)
#pragma unroll
      for (int n = 0; n < 4; ++n)
        acc[m][n] = __builtin_amdgcn_mfma_f32_16x16x32_bf16(af[m], bfr[n], acc[m][n], 0, 0, 0);
    __syncthreads();
  }
#pragma unroll
  for (int m = 0; m < 4; ++m) {
    int row0 = arow0 + wm * 64 + m * 16 + ((l >> 4) << 2);
#pragma unroll
    for (int n = 0; n < 4; ++n) {
      int col = bcol0 + wn * 64 + n * 16 + (l & 15);
      if (MODE == 0) {
        int mi = col >> 9;
        int hc = col & 511;
        const float* bp = mi == 0 ? bq : mi == 1 ? bk : bv;
        float bias = bp[hc];
        int head = hc >> 6, tt = hc & 63;
        bf16_t* base = qkv + (((size_t)mi * NH + head) * NNODES) * DT + tt;
#pragma unroll
        for (int r = 0; r < 4; ++r)
          base[(size_t)(row0 + r) * DT] = (bf16_t)(acc[m][n][r] + bias);
      } else {
        float bias = bo[col];
#pragma unroll
        for (int r = 0; r < 4; ++r)
          outp[(size_t)(row0 + r) * DTOT + col] = acc[m][n][r] + bias;
      }
    }
  }
}

// ---------------------------------------------------------------------------
// GENERAL ONLY: flash-style attention. Grid (128, 8); each wave loops 8 rows.
__global__ __launch_bounds__(256) void attn_kernel(
    const bf16_t* __restrict__ qkv, const float* __restrict__ adj,
    const float* __restrict__ alpha, const float* __restrict__ beta,
    bf16_t* __restrict__ z) {
  if (beta_all_zero(beta)) return;
  const int h = blockIdx.y;
  const int wv_ = threadIdx.x >> 6;
  const int l = threadIdx.x & 63;
  const float a = alpha[h], b = beta[h];
  const size_t hoff = (size_t)h * NNODES * DT;
  const bf16_t* Q = qkv + hoff;
  const bf16_t* Kh = qkv + (size_t)NH * NNODES * DT + hoff;
  const bf16_t* V = qkv + (size_t)2 * NH * NNODES * DT + hoff;
  __shared__ float qs[4][64];
  __shared__ float ps[4][64];

  for (int i = blockIdx.x * 4 + wv_; i < NNODES; i += 512) {
    if (b == 0.0f) {
      z[(size_t)i * DTOT + h * DT + l] = (bf16_t)(a * (float)V[(size_t)i * DT + l]);
      continue;
    }
    qs[wv_][l] = (float)Q[(size_t)i * DT + l];
    float mr = -__builtin_inff(), sr = 0.f, zacc = 0.f, sii = -__builtin_inff();
    const float* adjrow = adj + ((size_t)h * NNODES + i) * NNODES;
    __syncthreads();
    for (int c0 = 0; c0 < NNODES; c0 += 64) {
      int j = c0 + l;
      float s = 0.f;
      const bf16_t* kp = Kh + (size_t)j * DT;
#pragma unroll
      for (int d = 0; d < 64; ++d) s += qs[wv_][d] * (float)kp[d];
      s = s * 0.125f + adjrow[j];
      if ((i >> 6) == (c0 >> 6)) sii = __shfl(s, i & 63, 64);
      float cm = s;
#pragma unroll
      for (int o = 32; o; o >>= 1) cm = fmaxf(cm, __shfl_xor(cm, o, 64));
      float mn = fmaxf(mr, cm);
      float scale = expf(mr - mn);
      sr *= scale;
      zacc *= scale;
      float p = expf(s - mn);
      float cs = p;
#pragma unroll
      for (int o = 32; o; o >>= 1) cs += __shfl_xor(cs, o, 64);
      sr += cs;
      mr = mn;
      ps[wv_][l] = p;
      __syncthreads();
      float za = 0.f;
      for (int j2 = 0; j2 < 64; ++j2)
        za += ps[wv_][j2] * (float)V[(size_t)(c0 + j2) * DT + l];
      zacc += za;
      __syncthreads();
    }
    float pii = expf(sii - mr) / sr;
    float vd = (float)V[(size_t)i * DT + l];
    float zd = b * (zacc / sr) + (a - b * pii) * vd;
    z[(size_t)i * DTOT + h * DT + l] = (bf16_t)zd;
  }
}

// ---------------------------------------------------------------------------
extern "C" void kernel_launch(void* const* d_in, const int* in_sizes, int n_in,
                              void* d_out, int out_size, void* d_ws, size_t ws_size,
                              hipStream_t stream) {
  const float* x     = (const float*)d_in[0];
  const float* adj   = (const float*)d_in[1];
  const float* wq    = (const float*)d_in[2];
  const float* bq    = (const float*)d_in[3];
  const float* wk    = (const float*)d_in[4];
  const float* bk    = (const float*)d_in[5];
  const float* wv    = (const float*)d_in[6];
  const float* bv    = (const float*)d_in[7];
  const float* wo    = (const float*)d_in[8];
  const float* bo    = (const float*)d_in[9];
  const float* alpha = (const float*)d_in[10];
  const float* beta  = (const float*)d_in[11];
  float* out = (float*)d_out;
  char* ws = (char*)d_ws;

  bf16_t* xb     = (bf16_t*)(ws);                  // 4 MB
  bf16_t* wqkvT  = (bf16_t*)(ws + 4194304u);       // 1.5 MB
  bf16_t* woT    = (bf16_t*)(ws + 5767168u);       // 0.5 MB
  bf16_t* wv_s   = (bf16_t*)(ws + 6291456u);       // 0.5 MB
  bf16_t* w_effT = (bf16_t*)(ws + 6815744u);       // 0.5 MB
  float*  b_eff  = (float*)(ws + 7340032u);        // 2 KB
  bf16_t* qkv    = (bf16_t*)(ws + 8388608u);       // 12 MB
  bf16_t* z      = (bf16_t*)(ws + 20971520u);      // 4 MB

  hipLaunchKernelGGL(prep_kernel, dim3(2370), dim3(256), 0, stream,
                     x, wq, wk, wv, wo, bv, bo, alpha, beta,
                     xb, wqkvT, woT, wv_s, b_eff);
  hipLaunchKernelGGL(comp_gemm_kernel, dim3(8, 8), dim3(256), 0, stream,
                     woT, wv_s, beta, w_effT);
  hipLaunchKernelGGL(final_gemm_kernel, dim3(64, 4), dim3(256), 0, stream,
                     xb, w_effT, b_eff, beta, out);
  hipLaunchKernelGGL((gemm_kernel<0>), dim3(32, 12), dim3(256), 0, stream,
                     xb, wqkvT, bq, bk, bv, nullptr, beta, qkv, nullptr);
  hipLaunchKernelGGL(attn_kernel, dim3(128, 8), dim3(256), 0, stream,
                     qkv, adj, alpha, beta, z);
  hipLaunchKernelGGL((gemm_kernel<1>), dim3(32, 4), dim3(256), 0, stream,
                     z, woT, nullptr, nullptr, nullptr, bo, beta, nullptr, out);
}

// Round 4
// 32.618 us; speedup vs baseline: 1.5354x; 1.4517x over previous
//
#include <hip/hip_runtime.h>
#include <hip/hip_bf16.h>
#include <cstdint>
#include <cstddef>

typedef __bf16 bf16_t;
typedef __bf16 bf16x8 __attribute__((ext_vector_type(8)));
typedef __bf16 bf16x4 __attribute__((ext_vector_type(4)));
typedef float f32x4 __attribute__((ext_vector_type(4)));

#define NNODES 4096
#define EMB 512
#define NH 8
#define DT 64
#define DTOT 512  // NH*DT

// ---------------------------------------------------------------------------
__device__ __forceinline__ void async_copy16(void* lds, const void* gsrc) {
  __builtin_amdgcn_global_load_lds(
      (const __attribute__((address_space(1))) void*)gsrc,
      (__attribute__((address_space(3))) void*)lds, 16, 0, 0);
}

__device__ __forceinline__ bool beta_all_zero(const float* __restrict__ beta) {
  bool z = true;
#pragma unroll
  for (int h = 0; h < NH; ++h) z = z && (beta[h] == 0.0f);
  return z;
}

// ---------------------------------------------------------------------------
// Fused prep:
//   [0,2048)      x -> bf16
//   [2048,2112)   woT[n][d] = (bf16) wo[d][n]
//   [2112,2176)   wv_s[k][d] = (bf16)(wv[k][d] * alpha[d>>6])
//   [2176,2208)   partial_b[s][n] = sum_{d in 16-chunk s} bv[d]*alpha*wo[d][n]
//   [2208,2400)   general-only wq/wk/wv transposes (dead when beta==0)
__global__ __launch_bounds__(256) void prep_kernel(
    const float* __restrict__ x,
    const float* __restrict__ wq, const float* __restrict__ wk,
    const float* __restrict__ wv, const float* __restrict__ wo,
    const float* __restrict__ bv,
    const float* __restrict__ alpha, const float* __restrict__ beta,
    bf16_t* __restrict__ xb, bf16_t* __restrict__ wqkvT,
    bf16_t* __restrict__ woT, bf16_t* __restrict__ wv_s,
    float* __restrict__ partial_b) {
  __shared__ float tile[64][65];
  __shared__ float wls[16];
  int b = blockIdx.x;
  const int tid = threadIdx.x;
  if (b < 2048) {  // x -> bf16
    int i = b * 256 + tid;
    float4 v = reinterpret_cast<const float4*>(x)[i];
    bf16x4 o = {(bf16_t)v.x, (bf16_t)v.y, (bf16_t)v.z, (bf16_t)v.w};
    reinterpret_cast<bf16x4*>(xb)[i] = o;
    return;
  }
  b -= 2048;
  if (b < 64) {  // woT
    int kb = (b >> 3) << 6, nb = (b & 7) << 6;
    int c = tid & 63, r0 = tid >> 6;
    for (int r = r0; r < 64; r += 4)
      tile[r][c] = wo[(size_t)(kb + r) * EMB + nb + c];
    __syncthreads();
    for (int r = r0; r < 64; r += 4)
      woT[(size_t)(nb + r) * EMB + kb + c] = (bf16_t)tile[c][r];
    return;
  }
  b -= 64;
  if (b < 64) {  // wv_s
#pragma unroll
    for (int t = 0; t < 4; ++t) {
      int i = b * 1024 + t * 256 + tid;
      float4 v = reinterpret_cast<const float4*>(wv)[i];
      float sc = alpha[(i & 127) >> 4];
      bf16x4 o = {(bf16_t)(v.x * sc), (bf16_t)(v.y * sc),
                  (bf16_t)(v.z * sc), (bf16_t)(v.w * sc)};
      reinterpret_cast<bf16x4*>(wv_s)[i] = o;
    }
    return;
  }
  b -= 64;
  if (b < 32) {  // partial_b, split-K chunk of 16 d-rows
    if (tid < 16) wls[tid] = bv[b * 16 + tid] * alpha[(b * 16 + tid) >> 6];
    __syncthreads();
#pragma unroll
    for (int half = 0; half < 2; ++half) {
      int n = half * 256 + tid;
      float s = 0.f;
#pragma unroll
      for (int dd = 0; dd < 16; ++dd)
        s += wls[dd] * wo[(size_t)(b * 16 + dd) * EMB + n];
      partial_b[b * DTOT + n] = s;
    }
    return;
  }
  b -= 32;
  if (beta_all_zero(beta)) return;  // general-mode only below
  int mat = b >> 6;  // 0=q 1=k 2=v
  int t2 = b & 63;
  const float* src = mat == 0 ? wq : mat == 1 ? wk : wv;
  int kb = (t2 >> 3) << 6, nb = (t2 & 7) << 6;
  int c = tid & 63, r0 = tid >> 6;
  for (int r = r0; r < 64; r += 4)
    tile[r][c] = src[(size_t)(kb + r) * EMB + nb + c];
  __syncthreads();
  bf16_t* dst = wqkvT + (size_t)mat * EMB * DTOT;
  for (int r = r0; r < 64; r += 4)
    dst[(size_t)(nb + r) * EMB + kb + c] = (bf16_t)tile[c][r];
}

// ---------------------------------------------------------------------------
// FAST-PATH tiled GEMM: C[64x64] = A[64xK] * B[64xK]^T (both row-major,
// stride 512, K=512), BK=128, double-buffered (issue-early), XOR-swizzled
// LDS ([64][128] bf16; 16B-chunk index ^= row&7 on BOTH global-src and read).
// MODE 0 (comp): out w_effT bf16.  MODE 1 (final): out fp32 + bias from
// partial_b (32 split-K slices) + bo.
template <int MODE>
__global__ __launch_bounds__(256) void tile_gemm_kernel(
    const bf16_t* __restrict__ A, const bf16_t* __restrict__ B,
    const float* __restrict__ partial_b, const float* __restrict__ bo,
    const float* __restrict__ beta,
    bf16_t* __restrict__ outb, float* __restrict__ outf) {
  if (!beta_all_zero(beta)) return;
  __shared__ __align__(16) bf16_t sA[2][64 * 128];
  __shared__ __align__(16) bf16_t sB[2][64 * 128];
  __shared__ float bias_s[64];
  const int tid = threadIdx.x, l = tid & 63, w = tid >> 6;
  const int wm = w >> 1, wn = w & 1;
  const int row0 = blockIdx.x * 64, col0 = blockIdx.y * 64;

  // stage one [64][128] tile into buf: 4 issues/wave, 4 rows each.
  // source chunk pre-swizzled so that stored chunk kk == source chunk kk^(row&7).
#define STAGE_TILE(dst, G, grow0, k0)                                         \
  {                                                                           \
    _Pragma("unroll") for (int j = 0; j < 4; ++j) {                           \
      int rl = j * 16 + w * 4 + (l >> 4);                                     \
      int kk = (l & 15) ^ (rl & 7);                                           \
      async_copy16((dst) + (j * 16 + w * 4) * 128,                            \
                   &(G)[(size_t)((grow0) + rl) * 512 + (k0) + kk * 8]);       \
    }                                                                         \
  }

  f32x4 acc[2][2];
#pragma unroll
  for (int m = 0; m < 2; ++m)
#pragma unroll
    for (int n = 0; n < 2; ++n) acc[m][n] = f32x4{0.f, 0.f, 0.f, 0.f};

  STAGE_TILE(sA[0], A, row0, 0)
  STAGE_TILE(sB[0], B, col0, 0)
  __syncthreads();

#pragma unroll
  for (int t = 0; t < 4; ++t) {
    int cur = t & 1;
    if (t < 3) {  // issue next-tile loads BEFORE computing current
      STAGE_TILE(sA[cur ^ 1], A, row0, (t + 1) * 128)
      STAGE_TILE(sB[cur ^ 1], B, col0, (t + 1) * 128)
    }
#pragma unroll
    for (int ks = 0; ks < 4; ++ks) {
      bf16x8 af[2], bfr[2];
#pragma unroll
      for (int m = 0; m < 2; ++m) {
        int row = wm * 32 + m * 16 + (l & 15);
        int c = ks * 4 + (l >> 4);
        af[m] = *(const bf16x8*)&sA[cur][row * 128 + ((c ^ (row & 7)) << 3)];
      }
#pragma unroll
      for (int n = 0; n < 2; ++n) {
        int row = wn * 32 + n * 16 + (l & 15);
        int c = ks * 4 + (l >> 4);
        bfr[n] = *(const bf16x8*)&sB[cur][row * 128 + ((c ^ (row & 7)) << 3)];
      }
#pragma unroll
      for (int m = 0; m < 2; ++m)
#pragma unroll
        for (int n = 0; n < 2; ++n)
          acc[m][n] = __builtin_amdgcn_mfma_f32_16x16x32_bf16(af[m], bfr[n], acc[m][n], 0, 0, 0);
    }
    __syncthreads();  // drains next-tile loads; buf[cur^1] ready for t+1
  }

  if (MODE == 1) {  // bias: bo + 32 split-K partials, staged once per block
    if (tid < 64) {
      float s = bo[col0 + tid];
#pragma unroll
      for (int p = 0; p < 32; ++p) s += partial_b[p * DTOT + col0 + tid];
      bias_s[tid] = s;
    }
    __syncthreads();
  }

#pragma unroll
  for (int m = 0; m < 2; ++m) {
    int r0 = row0 + wm * 32 + m * 16 + ((l >> 4) << 2);
#pragma unroll
    for (int n = 0; n < 2; ++n) {
      int cl = wn * 32 + n * 16 + (l & 15);
      if (MODE == 0) {
#pragma unroll
        for (int r = 0; r < 4; ++r)
          outb[(size_t)(r0 + r) * EMB + col0 + cl] = (bf16_t)acc[m][n][r];
      } else {
        float bias = bias_s[cl];
#pragma unroll
        for (int r = 0; r < 4; ++r)
          outf[(size_t)(r0 + r) * DTOT + col0 + cl] = acc[m][n][r] + bias;
      }
    }
  }
#undef STAGE_TILE
}

// ---------------------------------------------------------------------------
// GENERAL ONLY (dead-launch when all beta==0): QKV / output projection GEMM.
template <int MODE>
__global__ __launch_bounds__(256) void gemm_kernel(
    const bf16_t* __restrict__ A, const bf16_t* __restrict__ B,
    const float* __restrict__ bq, const float* __restrict__ bk,
    const float* __restrict__ bv, const float* __restrict__ bo,
    const float* __restrict__ beta,
    bf16_t* __restrict__ qkv, float* __restrict__ outp) {
  if (beta_all_zero(beta)) return;
  constexpr int K = 512;
  __shared__ __align__(16) bf16_t sA[128 * 32];
  __shared__ __align__(16) bf16_t sB[128 * 32];
  const int tid = threadIdx.x;
  const int l = tid & 63, w = tid >> 6;
  const int wm = w >> 1, wn = w & 1;
  const int arow0 = blockIdx.x * 128;
  const int bcol0 = blockIdx.y * 128;
  f32x4 acc[4][4];
#pragma unroll
  for (int m = 0; m < 4; ++m)
#pragma unroll
    for (int n = 0; n < 4; ++n) acc[m][n] = f32x4{0.f, 0.f, 0.f, 0.f};
  for (int kt = 0; kt < K; kt += 32) {
#pragma unroll
    for (int i = 0; i < 2; ++i) {
      int row = (i << 6) + (w << 4) + (l >> 2);
      int cole = (l & 3) << 3;
      int ldso = i * 2048 + w * 512;
      async_copy16(&sA[ldso], &A[(size_t)(arow0 + row) * K + kt + cole]);
      async_copy16(&sB[ldso], &B[(size_t)(bcol0 + row) * K + kt + cole]);
    }
    __syncthreads();
    bf16x8 af[4], bfr[4];
#pragma unroll
    for (int m = 0; m < 4; ++m)
      af[m] = *(const bf16x8*)&sA[(wm * 64 + m * 16 + (l & 15)) * 32 + ((l >> 4) << 3)];
#pragma unroll
    for (int n = 0; n < 4; ++n)
      bfr[n] = *(const bf16x8*)&sB[(wn * 64 + n * 16 + (l & 15)) * 32 + ((l >> 4) << 3)];
#pragma unroll
    for (int m = 0; m < 4; ++m)
#pragma unroll
      for (int n = 0; n < 4; ++n)
        acc[m][n] = __builtin_amdgcn_mfma_f32_16x16x32_bf16(af[m], bfr[n], acc[m][n], 0, 0, 0);
    __syncthreads();
  }
#pragma unroll
  for (int m = 0; m < 4; ++m) {
    int row0 = arow0 + wm * 64 + m * 16 + ((l >> 4) << 2);
#pragma unroll
    for (int n = 0; n < 4; ++n) {
      int col = bcol0 + wn * 64 + n * 16 + (l & 15);
      if (MODE == 0) {
        int mi = col >> 9;
        int hc = col & 511;
        const float* bp = mi == 0 ? bq : mi == 1 ? bk : bv;
        float bias = bp[hc];
        int head = hc >> 6, tt = hc & 63;
        bf16_t* base = qkv + (((size_t)mi * NH + head) * NNODES) * DT + tt;
#pragma unroll
        for (int r = 0; r < 4; ++r)
          base[(size_t)(row0 + r) * DT] = (bf16_t)(acc[m][n][r] + bias);
      } else {
        float bias = bo[col];
#pragma unroll
        for (int r = 0; r < 4; ++r)
          outp[(size_t)(row0 + r) * DTOT + col] = acc[m][n][r] + bias;
      }
    }
  }
}

// ---------------------------------------------------------------------------
// GENERAL ONLY: flash-style attention. Grid (128, 8); each wave loops 8 rows.
__global__ __launch_bounds__(256) void attn_kernel(
    const bf16_t* __restrict__ qkv, const float* __restrict__ adj,
    const float* __restrict__ alpha, const float* __restrict__ beta,
    bf16_t* __restrict__ z) {
  if (beta_all_zero(beta)) return;
  const int h = blockIdx.y;
  const int wv_ = threadIdx.x >> 6;
  const int l = threadIdx.x & 63;
  const float a = alpha[h], b = beta[h];
  const size_t hoff = (size_t)h * NNODES * DT;
  const bf16_t* Q = qkv + hoff;
  const bf16_t* Kh = qkv + (size_t)NH * NNODES * DT + hoff;
  const bf16_t* V = qkv + (size_t)2 * NH * NNODES * DT + hoff;
  __shared__ float qs[4][64];
  __shared__ float ps[4][64];

  for (int i = blockIdx.x * 4 + wv_; i < NNODES; i += 512) {
    if (b == 0.0f) {
      z[(size_t)i * DTOT + h * DT + l] = (bf16_t)(a * (float)V[(size_t)i * DT + l]);
      continue;
    }
    qs[wv_][l] = (float)Q[(size_t)i * DT + l];
    float mr = -__builtin_inff(), sr = 0.f, zacc = 0.f, sii = -__builtin_inff();
    const float* adjrow = adj + ((size_t)h * NNODES + i) * NNODES;
    __syncthreads();
    for (int c0 = 0; c0 < NNODES; c0 += 64) {
      int j = c0 + l;
      float s = 0.f;
      const bf16_t* kp = Kh + (size_t)j * DT;
#pragma unroll
      for (int d = 0; d < 64; ++d) s += qs[wv_][d] * (float)kp[d];
      s = s * 0.125f + adjrow[j];
      if ((i >> 6) == (c0 >> 6)) sii = __shfl(s, i & 63, 64);
      float cm = s;
#pragma unroll
      for (int o = 32; o; o >>= 1) cm = fmaxf(cm, __shfl_xor(cm, o, 64));
      float mn = fmaxf(mr, cm);
      float scale = expf(mr - mn);
      sr *= scale;
      zacc *= scale;
      float p = expf(s - mn);
      float cs = p;
#pragma unroll
      for (int o = 32; o; o >>= 1) cs += __shfl_xor(cs, o, 64);
      sr += cs;
      mr = mn;
      ps[wv_][l] = p;
      __syncthreads();
      float za = 0.f;
      for (int j2 = 0; j2 < 64; ++j2)
        za += ps[wv_][j2] * (float)V[(size_t)(c0 + j2) * DT + l];
      zacc += za;
      __syncthreads();
    }
    float pii = expf(sii - mr) / sr;
    float vd = (float)V[(size_t)i * DT + l];
    float zd = b * (zacc / sr) + (a - b * pii) * vd;
    z[(size_t)i * DTOT + h * DT + l] = (bf16_t)zd;
  }
}

// ---------------------------------------------------------------------------
extern "C" void kernel_launch(void* const* d_in, const int* in_sizes, int n_in,
                              void* d_out, int out_size, void* d_ws, size_t ws_size,
                              hipStream_t stream) {
  const float* x     = (const float*)d_in[0];
  const float* adj   = (const float*)d_in[1];
  const float* wq    = (const float*)d_in[2];
  const float* bq    = (const float*)d_in[3];
  const float* wk    = (const float*)d_in[4];
  const float* bk    = (const float*)d_in[5];
  const float* wv    = (const float*)d_in[6];
  const float* bv    = (const float*)d_in[7];
  const float* wo    = (const float*)d_in[8];
  const float* bo    = (const float*)d_in[9];
  const float* alpha = (const float*)d_in[10];
  const float* beta  = (const float*)d_in[11];
  float* out = (float*)d_out;
  char* ws = (char*)d_ws;

  bf16_t* xb        = (bf16_t*)(ws);              // 4 MB
  bf16_t* wqkvT     = (bf16_t*)(ws + 4194304u);   // 1.5 MB
  bf16_t* woT       = (bf16_t*)(ws + 5767168u);   // 0.5 MB
  bf16_t* wv_s      = (bf16_t*)(ws + 6291456u);   // 0.5 MB
  bf16_t* w_effT    = (bf16_t*)(ws + 6815744u);   // 0.5 MB
  float*  partial_b = (float*)(ws + 7340032u);    // 64 KB
  bf16_t* qkv       = (bf16_t*)(ws + 8388608u);   // 12 MB
  bf16_t* z         = (bf16_t*)(ws + 20971520u);  // 4 MB

  hipLaunchKernelGGL(prep_kernel, dim3(2400), dim3(256), 0, stream,
                     x, wq, wk, wv, wo, bv, alpha, beta,
                     xb, wqkvT, woT, wv_s, partial_b);
  // comp: w_effT[n][k] = sum_d woT[n][d] * wv_s[k][d]
  hipLaunchKernelGGL((tile_gemm_kernel<0>), dim3(8, 8), dim3(256), 0, stream,
                     woT, wv_s, nullptr, nullptr, beta, w_effT, nullptr);
  // final: out[m][n] = sum_k xb[m][k] * w_effT[n][k] + bias[n]
  hipLaunchKernelGGL((tile_gemm_kernel<1>), dim3(64, 8), dim3(256), 0, stream,
                     xb, w_effT, partial_b, bo, beta, nullptr, out);
  hipLaunchKernelGGL((gemm_kernel<0>), dim3(32, 12), dim3(256), 0, stream,
                     xb, wqkvT, bq, bk, bv, nullptr, beta, qkv, nullptr);
  hipLaunchKernelGGL(attn_kernel, dim3(128, 8), dim3(256), 0, stream,
                     qkv, adj, alpha, beta, z);
  hipLaunchKernelGGL((gemm_kernel<1>), dim3(32, 4), dim3(256), 0, stream,
                     z, woT, nullptr, nullptr, nullptr, bo, beta, nullptr, out);
}